// Round 16
// baseline (303.800 us; speedup 1.0000x reference)
//
#include <hip/hip_runtime.h>
#include <hip/hip_bf16.h>

// B=32, N=1024, D=768, H=12, d=64. Real tokens M=32768.
// Pad token handled analytically: ksum += 1.0 per component, kv/output unaffected.

typedef __bf16 bf16x8 __attribute__((ext_vector_type(8)));
typedef float f32x4 __attribute__((ext_vector_type(4)));

#define SBAR  __builtin_amdgcn_sched_barrier(0)

__device__ __forceinline__ ushort f2bf(float f) {
  union { float f; unsigned u; } x; x.f = f;
  unsigned r = x.u + 0x7fffu + ((x.u >> 16) & 1u);   // RNE
  return (ushort)(r >> 16);
}
__device__ __forceinline__ float bf2f(ushort h) {
  union { unsigned u; float f; } x; x.u = ((unsigned)h) << 16;
  return x.f;
}
__device__ __forceinline__ float bits2f(unsigned u) {
  union { unsigned u; float f; } x; x.u = u;
  return x.f;
}
__device__ __forceinline__ void gload_lds16(const void* g, void* lds) {
  __builtin_amdgcn_global_load_lds((const __attribute__((address_space(1))) void*)g,
                                   (__attribute__((address_space(3))) void*)lds, 16, 0, 0);
}

// ---------------- fp32 -> bf16 elementwise (x4 vectorized) ----------------
__global__ __launch_bounds__(256) void cvt_f32_bf16(const float* __restrict__ in,
                                                    ushort* __restrict__ out, int n4) {
  int i = blockIdx.x * 256 + threadIdx.x;
  if (i >= n4) return;
  float4 v = reinterpret_cast<const float4*>(in)[i];
  ushort4 o;
  o.x = f2bf(v.x); o.y = f2bf(v.y); o.z = f2bf(v.z); o.w = f2bf(v.w);
  reinterpret_cast<ushort4*>(out)[i] = o;
}

// ---------------- merged transpose+convert (both weight matrices, one launch) -------
// z=0: W_qkv [768][2304] -> [2304][768] bf16; z=1: W_out [768][768] -> [768][768]^T
__global__ __launch_bounds__(256) void transpose_cvt2(const float* __restrict__ srcA,
                                                      ushort* __restrict__ dstA,
                                                      const float* __restrict__ srcB,
                                                      ushort* __restrict__ dstB) {
  const float* src; ushort* dst; int R, C;
  if (blockIdx.z == 0) { src = srcA; dst = dstA; R = 768; C = 2304; }
  else                 { if (blockIdx.x >= 24) return; src = srcB; dst = dstB; R = 768; C = 768; }
  __shared__ float tile[32][33];
  int bc = blockIdx.x * 32, br = blockIdx.y * 32;
  int tx = threadIdx.x & 31, ty = threadIdx.x >> 5;   // 32x8
  #pragma unroll
  for (int i = 0; i < 32; i += 8)
    tile[ty + i][tx] = src[(size_t)(br + ty + i) * C + (bc + tx)];
  __syncthreads();
  #pragma unroll
  for (int i = 0; i < 32; i += 8)
    dst[(size_t)(bc + ty + i) * R + (br + tx)] = f2bf(tile[tx][ty + i]);
}

// ==================== 128x256 triple-buffered 2-resident GEMM (r11 optimum) =========
// C[M][N] = A[M][K] * Bt[N][K]^T, bf16 in, fp32 accum.
// 512 threads = 8 waves (2M x 4N), per-wave 64x64 out. BK=32, NT=K/32, 1 phase/tile.
// LDS = 3 bufs x 24 KB { A[128][32] | B[256][32] } = 72 KB -> 2 blocks/CU.
// Phase t: frag reads buf[t%3] -> stage tile t+2 into buf[(t+2)%3] (3 loads) ->
// vmcnt(3) (confirms t+1, never drains) -> barrier -> 16 MFMA -> barrier.
// Cross-block overlap (2 independent blocks/CU) hides the within-block
// serialization that capped 1-resident configs (r2-r10). Measured 141 us (r11).
// MODE 0: epilogue phi on cols<1536, store bf16.  MODE 1: +bias, store fp32.
template <int MODE>
__global__ __launch_bounds__(512, 4) void gemm3b(const ushort* __restrict__ A,
                                                 const ushort* __restrict__ Bt,
                                                 void* __restrict__ C,
                                                 const float* __restrict__ bias,
                                                 int N, int K, int nbx, int cpx) {
  extern __shared__ ushort lds[];
  const int tid = threadIdx.x;
  const int lane = tid & 63;
  const int wid = tid >> 6;
  const int wm = wid >> 2, wn = wid & 3;
  const int laneR = lane & 15, laneS = lane >> 4;

  // XCD-bijective swizzle (nwg % 8 == 0), bx-fastest within chunk
  const int bid = blockIdx.x;
  const int lin = (bid & 7) * cpx + (bid >> 3);
  const int by = lin / nbx, bx = lin - by * nbx;
  const int m0 = by * 128, n0 = bx * 256;
  const int NT = K >> 5;

  const int sr = tid >> 2, ss = tid & 3;
  const int sslot = ss ^ ((sr >> 1) & 3);
  const ushort* Asrc = A + (size_t)(m0 + sr) * K + sslot * 8;
  const ushort* Bsrc = Bt + (size_t)(n0 + sr) * K + sslot * 8;
  const size_t rowstep128 = (size_t)128 * K;
  const int ldstA = tid * 8;
  const int ldstB = 4096 + tid * 8;

  const int sprime = laneS ^ ((laneR >> 1) & 3);
  const int aoff = (wm * 64 + laneR) * 32 + sprime * 8;
  const int boff = 4096 + (wn * 64 + laneR) * 32 + sprime * 8;

  f32x4 acc[4][4] = {};

  #define STAGE_T(KT, DB)                                                         \
    { gload_lds16(Asrc + (KT) * 32, lds + (DB) + ldstA);                          \
      gload_lds16(Bsrc + (KT) * 32, lds + (DB) + ldstB);                          \
      gload_lds16(Bsrc + (KT) * 32 + rowstep128, lds + (DB) + ldstB + 4096); }

  STAGE_T(0, 0);
  STAGE_T(1, 12288);
  asm volatile("s_waitcnt vmcnt(3)" ::: "memory");
  SBAR;
  __builtin_amdgcn_s_barrier();
  SBAR;

  for (int t = 0; t < NT; ++t) {
    const ushort* cb = lds + (t % 3) * 12288;
    const int db2 = ((t + 2) % 3) * 12288;
    const int t2 = (t + 2 < NT) ? t + 2 : t;   // clamped tail: dead dup stages
    bf16x8 a[4], b[4];
    #pragma unroll
    for (int j = 0; j < 4; ++j) b[j] = *(const bf16x8*)(cb + boff + j * 512);
    #pragma unroll
    for (int i = 0; i < 4; ++i) a[i] = *(const bf16x8*)(cb + aoff + i * 512);
    STAGE_T(t2, db2);
    asm volatile("s_waitcnt vmcnt(3)" ::: "memory");   // confirms tile t+1
    SBAR;
    __builtin_amdgcn_s_barrier();
    SBAR;
    __builtin_amdgcn_s_setprio(1);
    #pragma unroll
    for (int i = 0; i < 4; ++i)
      #pragma unroll
      for (int j = 0; j < 4; ++j)
        acc[i][j] = __builtin_amdgcn_mfma_f32_16x16x32_bf16(a[i], b[j], acc[i][j], 0, 0, 0);
    __builtin_amdgcn_s_setprio(0);
    SBAR;
    __builtin_amdgcn_s_barrier();
    SBAR;
  }
  #undef STAGE_T
  asm volatile("s_waitcnt vmcnt(0)" ::: "memory");     // drain dead tail stages

  // ---- epilogue: C/D layout col=lane&15, row=(lane>>4)*4+r ----
  #pragma unroll
  for (int i = 0; i < 4; ++i) {
    const int grow0 = m0 + wm * 64 + i * 16 + (laneS << 2);
    #pragma unroll
    for (int j = 0; j < 4; ++j) {
      const int gcol = n0 + wn * 64 + j * 16 + laneR;
      #pragma unroll
      for (int r = 0; r < 4; ++r) {
        float v = acc[i][j][r];
        if (MODE == 0) {
          if (gcol < 1536) v = (v > 0.f) ? (v + 1.f) : __expf(v);   // phi on q,k
          reinterpret_cast<ushort*>(C)[(size_t)(grow0 + r) * N + gcol] = f2bf(v);
        } else {
          reinterpret_cast<float*>(C)[(size_t)(grow0 + r) * N + gcol] = v + bias[gcol];
        }
      }
    }
  }
}

// ---------------- kv full: one block per (b,h); kvbf + ksum(+1) written DIRECTLY ----
// Replaces kv_partial(4-split) + kv_reduce: no f32 partial round-trip, one fewer
// kernel+gap. f32-in-LDS staging (convert once), stride-68 pad (write <=2-way).
__global__ __launch_bounds__(256) void kv_full(const ushort* __restrict__ qkv,
                                               ushort* __restrict__ kv_bf,
                                               float* __restrict__ ksum) {
  const int bh = blockIdx.x;           // 384
  const int b = bh / 12, h = bh % 12;
  const int tid = threadIdx.x;
  __shared__ float Ks[32 * 68];
  __shared__ float Vs[32 * 68];
  float acc[4][4] = {};                // [m][dq]
  float kacc[4] = {};
  const int dq0 = (tid & 15) * 4, mq0 = (tid >> 4) * 4;
  const int r = tid >> 3, o = (tid & 7) * 8;        // stage: row r, 8 cols from o
  for (int st = 0; st < 1024; st += 32) {
    const size_t rowbase = (size_t)(b * 1024 + st + r) * 2304 + h * 64 + o;
    int4 kraw = *reinterpret_cast<const int4*>(qkv + rowbase + 768);
    int4 vraw = *reinterpret_cast<const int4*>(qkv + rowbase + 1536);
    float kf[8], vf[8];
    {
      const unsigned* kw = reinterpret_cast<const unsigned*>(&kraw);
      const unsigned* vw = reinterpret_cast<const unsigned*>(&vraw);
      #pragma unroll
      for (int w = 0; w < 4; ++w) {
        kf[2 * w]     = bits2f(kw[w] << 16);
        kf[2 * w + 1] = bits2f(kw[w] & 0xffff0000u);
        vf[2 * w]     = bits2f(vw[w] << 16);
        vf[2 * w + 1] = bits2f(vw[w] & 0xffff0000u);
      }
    }
    __syncthreads();                   // prev-iter LDS reads done
    #pragma unroll
    for (int w = 0; w < 8; ++w) {
      Ks[r * 68 + o + w] = kf[w];
      Vs[r * 68 + o + w] = vf[w];
    }
    __syncthreads();                   // tile present
    #pragma unroll 8
    for (int s = 0; s < 32; ++s) {
      f32x4 kk = *reinterpret_cast<const f32x4*>(&Ks[s * 68 + dq0]);
      f32x4 vv = *reinterpret_cast<const f32x4*>(&Vs[s * 68 + mq0]);
      #pragma unroll
      for (int jm = 0; jm < 4; ++jm)
        #pragma unroll
        for (int id = 0; id < 4; ++id)
          acc[jm][id] += vv[jm] * kk[id];
      if (mq0 == 0) {
        #pragma unroll
        for (int id = 0; id < 4; ++id) kacc[id] += kk[id];
      }
    }
  }
  ushort* kvp = kv_bf + (size_t)bh * 4096;
  #pragma unroll
  for (int jm = 0; jm < 4; ++jm)
    #pragma unroll
    for (int id = 0; id < 4; ++id)
      kvp[(mq0 + jm) * 64 + dq0 + id] = f2bf(acc[jm][id]);
  if (mq0 == 0) {
    #pragma unroll
    for (int id = 0; id < 4; ++id)
      ksum[(size_t)bh * 64 + dq0 + id] = kacc[id] + 1.0f;   // +1: pad token phi(0)=1
  }
}

// ---------------- attention (r13-verified: swizzled Qs/KVs, vectorized z-dot) -------
// z-dot pairing: LDS slot (s^tx7) of row tid CONTAINS global slot s (staging wrote
// source slot dsl^(qr&7) into linear dest slot dsl) -> multiply by ks_lds[s*8+...].
__global__ __launch_bounds__(256) void attn_kernel(const ushort* __restrict__ qkv,
                                                   const ushort* __restrict__ kv_bf,
                                                   const float* __restrict__ ksum,
                                                   ushort* __restrict__ attn) {
  const int blk = blockIdx.x;          // 384*8
  const int bh = blk >> 3, tb = blk & 7;
  const int b = bh / 12, h = bh % 12;
  const int row0 = b * 1024 + tb * 128;
  __shared__ ushort Qs[128 * 64];
  __shared__ ushort KVs[64 * 64];      // [m][dq]
  __shared__ float zs[128];
  __shared__ float ks_lds[64];
  const int tid = threadIdx.x;
  const int lane = tid & 63, w = tid >> 6;
  #pragma unroll
  for (int j = 0; j < 4; ++j) {
    int c = j * 256 + tid;
    int qr = c >> 3, dsl = c & 7;
    int ssl = dsl ^ (qr & 7);
    gload_lds16(qkv + (size_t)(row0 + qr) * 2304 + h * 64 + ssl * 8, &Qs[c * 8]);
  }
  #pragma unroll
  for (int j = 0; j < 2; ++j) {
    int c = j * 256 + tid;
    int mr = c >> 3, dsl = c & 7;
    int ssl = dsl ^ (mr & 7);
    gload_lds16(kv_bf + (size_t)bh * 4096 + mr * 64 + ssl * 8, &KVs[c * 8]);
  }
  if (tid < 64) ks_lds[tid] = ksum[bh * 64 + tid];
  asm volatile("s_waitcnt vmcnt(0)" ::: "memory");
  __syncthreads();
  if (tid < 128) {
    float d = 0.f;
    const int tx7 = tid & 7;
    #pragma unroll
    for (int s = 0; s < 8; ++s) {
      int4 raw = *reinterpret_cast<const int4*>(&Qs[tid * 64 + ((s ^ tx7) << 3)]);
      const unsigned* wds = reinterpret_cast<const unsigned*>(&raw);
      #pragma unroll
      for (int w2 = 0; w2 < 4; ++w2) {
        d += bits2f(wds[w2] << 16) * ks_lds[s * 8 + 2 * w2];
        d += bits2f(wds[w2] & 0xffff0000u) * ks_lds[s * 8 + 2 * w2 + 1];
      }
    }
    zs[tid] = 1.f / (d + 1e-6f);
  }
  __syncthreads();
  f32x4 acc[2][4] = {};
  const int lr7 = (lane & 15) & 7;
  #pragma unroll
  for (int ks = 0; ks < 2; ++ks) {
    const int sxor = ((ks * 4 + (lane >> 4)) ^ lr7) << 3;
    bf16x8 a[2], bb[4];
    #pragma unroll
    for (int i = 0; i < 2; ++i)
      a[i] = *reinterpret_cast<const bf16x8*>(&Qs[(w * 32 + i * 16 + (lane & 15)) * 64 + sxor]);
    #pragma unroll
    for (int j = 0; j < 4; ++j)
      bb[j] = *reinterpret_cast<const bf16x8*>(&KVs[(j * 16 + (lane & 15)) * 64 + sxor]);
    #pragma unroll
    for (int i = 0; i < 2; ++i)
      #pragma unroll
      for (int j = 0; j < 4; ++j)
        acc[i][j] = __builtin_amdgcn_mfma_f32_16x16x32_bf16(a[i], bb[j], acc[i][j], 0, 0, 0);
  }
  #pragma unroll
  for (int i = 0; i < 2; ++i) {
    const int t0 = w * 32 + i * 16 + ((lane >> 4) << 2);
    #pragma unroll
    for (int j = 0; j < 4; ++j) {
      const int m = j * 16 + (lane & 15);
      #pragma unroll
      for (int r = 0; r < 4; ++r) {
        float v = acc[i][j][r] * zs[t0 + r];
        attn[(size_t)(row0 + t0 + r) * 768 + h * 64 + m] = f2bf(v);
      }
    }
  }
}

// ---------------- launch ----------------
extern "C" void kernel_launch(void* const* d_in, const int* in_sizes, int n_in,
                              void* d_out, int out_size, void* d_ws, size_t ws_size,
                              hipStream_t stream) {
  (void)in_sizes; (void)n_in; (void)out_size; (void)ws_size;
  const float* x    = (const float*)d_in[0];
  const float* Wqkv = (const float*)d_in[1];
  const float* Wout = (const float*)d_in[2];
  const float* bout = (const float*)d_in[3];
  float* out = (float*)d_out;
  char* ws = (char*)d_ws;

  // workspace layout (total ~210 MB); region 0 reused by time-disjoint buffers
  ushort* xbf    = (ushort*)(ws);               // 50,331,648 B : x bf16 [32768][768]
  ushort* wqkvT  = (ushort*)(ws + 50331648);    //  3,538,944 B : W_qkv^T bf16 [2304][768]
  ushort* woutT  = (ushort*)(ws + 53870592);    //  1,179,648 B : W_out^T bf16 [768][768]
  ushort* qkv    = (ushort*)(ws + 55050240);    // 150,994,944 B: phi(q)|phi(k)|v bf16 [32768][2304]
  ushort* kvbf   = (ushort*)(ws + 206438400);   //  3,145,728 B : kv bf16 [384][64m][64dq]
  float*  ksum   = (float*) (ws + 209584128);   //     98,304 B : ksum+1 [384][64]
  ushort* attn   = (ushort*)(ws);               // 50,331,648 B : overlays xbf (dead after gemm1)

  static const int LDS3 = 73728;    // 3 bufs x 24 KB
  hipFuncSetAttribute(reinterpret_cast<const void*>(&gemm3b<0>),
                      hipFuncAttributeMaxDynamicSharedMemorySize, LDS3);
  hipFuncSetAttribute(reinterpret_cast<const void*>(&gemm3b<1>),
                      hipFuncAttributeMaxDynamicSharedMemorySize, LDS3);

  cvt_f32_bf16<<<24576, 256, 0, stream>>>(x, xbf, 6291456);
  transpose_cvt2<<<dim3(72, 24, 2), 256, 0, stream>>>(Wqkv, wqkvT, Wout, woutT);
  // GEMM1: 128x256 tiles -> grid 256x9 = 2304 (cpx=288), 2 blocks/CU  [141 us]
  gemm3b<0><<<2304, 512, LDS3, stream>>>(xbf, wqkvT, qkv, nullptr, 2304, 768, 9, 288);
  // kv: one block per (b,h); direct kvbf + ksum write (no reduce pass)
  kv_full<<<384, 256, 0, stream>>>(qkv, kvbf, ksum);
  attn_kernel<<<3072, 256, 0, stream>>>(qkv, kvbf, ksum, attn);
  // GEMM2: 128x256 tiles -> grid 256x3 = 768 (cpx=96)
  gemm3b<1><<<768, 512, LDS3, stream>>>(attn, woutT, out, bout, 768, 768, 3, 96);
}

// Round 17
// 288.983 us; speedup vs baseline: 1.0513x; 1.0513x over previous
//
#include <hip/hip_runtime.h>
#include <hip/hip_bf16.h>

// B=32, N=1024, D=768, H=12, d=64. Real tokens M=32768.
// Pad token handled analytically: ksum += 1.0 per component, kv/output unaffected.
// FINAL CONFIG (r15-measured 291.9 us): cvt + transpose_cvt2 + gemm3b<0> (141 us)
// + kv_partial(4-split) + kv_reduce + attn + gemm3b<1>.

typedef __bf16 bf16x8 __attribute__((ext_vector_type(8)));
typedef float f32x4 __attribute__((ext_vector_type(4)));

#define SBAR  __builtin_amdgcn_sched_barrier(0)

__device__ __forceinline__ ushort f2bf(float f) {
  union { float f; unsigned u; } x; x.f = f;
  unsigned r = x.u + 0x7fffu + ((x.u >> 16) & 1u);   // RNE
  return (ushort)(r >> 16);
}
__device__ __forceinline__ float bf2f(ushort h) {
  union { unsigned u; float f; } x; x.u = ((unsigned)h) << 16;
  return x.f;
}
__device__ __forceinline__ float bits2f(unsigned u) {
  union { unsigned u; float f; } x; x.u = u;
  return x.f;
}
__device__ __forceinline__ void gload_lds16(const void* g, void* lds) {
  __builtin_amdgcn_global_load_lds((const __attribute__((address_space(1))) void*)g,
                                   (__attribute__((address_space(3))) void*)lds, 16, 0, 0);
}

// ---------------- fp32 -> bf16 elementwise (x4 vectorized) ----------------
__global__ __launch_bounds__(256) void cvt_f32_bf16(const float* __restrict__ in,
                                                    ushort* __restrict__ out, int n4) {
  int i = blockIdx.x * 256 + threadIdx.x;
  if (i >= n4) return;
  float4 v = reinterpret_cast<const float4*>(in)[i];
  ushort4 o;
  o.x = f2bf(v.x); o.y = f2bf(v.y); o.z = f2bf(v.z); o.w = f2bf(v.w);
  reinterpret_cast<ushort4*>(out)[i] = o;
}

// ---------------- merged transpose+convert (both weight matrices, one launch) -------
// z=0: W_qkv [768][2304] -> [2304][768] bf16; z=1: W_out [768][768] -> [768][768]^T
__global__ __launch_bounds__(256) void transpose_cvt2(const float* __restrict__ srcA,
                                                      ushort* __restrict__ dstA,
                                                      const float* __restrict__ srcB,
                                                      ushort* __restrict__ dstB) {
  const float* src; ushort* dst; int R, C;
  if (blockIdx.z == 0) { src = srcA; dst = dstA; R = 768; C = 2304; }
  else                 { if (blockIdx.x >= 24) return; src = srcB; dst = dstB; R = 768; C = 768; }
  __shared__ float tile[32][33];
  int bc = blockIdx.x * 32, br = blockIdx.y * 32;
  int tx = threadIdx.x & 31, ty = threadIdx.x >> 5;   // 32x8
  #pragma unroll
  for (int i = 0; i < 32; i += 8)
    tile[ty + i][tx] = src[(size_t)(br + ty + i) * C + (bc + tx)];
  __syncthreads();
  #pragma unroll
  for (int i = 0; i < 32; i += 8)
    dst[(size_t)(bc + ty + i) * R + (br + tx)] = f2bf(tile[tx][ty + i]);
}

// ==================== 128x256 triple-buffered 2-resident GEMM (r11 optimum) =========
// C[M][N] = A[M][K] * Bt[N][K]^T, bf16 in, fp32 accum.
// 512 threads = 8 waves (2M x 4N), per-wave 64x64 out. BK=32, NT=K/32, 1 phase/tile.
// LDS = 3 bufs x 24 KB { A[128][32] | B[256][32] } = 72 KB -> 2 blocks/CU.
// Phase t: frag reads buf[t%3] -> stage tile t+2 into buf[(t+2)%3] (3 loads) ->
// vmcnt(3) (confirms t+1, never drains) -> barrier -> 16 MFMA -> barrier.
// Cross-block overlap (2 independent blocks/CU) hides the within-block
// serialization that capped 1-resident configs (r2-r10). Measured 141 us.
// MODE 0: epilogue phi on cols<1536, store bf16.  MODE 1: +bias, store fp32.
template <int MODE>
__global__ __launch_bounds__(512, 4) void gemm3b(const ushort* __restrict__ A,
                                                 const ushort* __restrict__ Bt,
                                                 void* __restrict__ C,
                                                 const float* __restrict__ bias,
                                                 int N, int K, int nbx, int cpx) {
  extern __shared__ ushort lds[];
  const int tid = threadIdx.x;
  const int lane = tid & 63;
  const int wid = tid >> 6;
  const int wm = wid >> 2, wn = wid & 3;
  const int laneR = lane & 15, laneS = lane >> 4;

  // XCD-bijective swizzle (nwg % 8 == 0), bx-fastest within chunk
  const int bid = blockIdx.x;
  const int lin = (bid & 7) * cpx + (bid >> 3);
  const int by = lin / nbx, bx = lin - by * nbx;
  const int m0 = by * 128, n0 = bx * 256;
  const int NT = K >> 5;

  const int sr = tid >> 2, ss = tid & 3;
  const int sslot = ss ^ ((sr >> 1) & 3);
  const ushort* Asrc = A + (size_t)(m0 + sr) * K + sslot * 8;
  const ushort* Bsrc = Bt + (size_t)(n0 + sr) * K + sslot * 8;
  const size_t rowstep128 = (size_t)128 * K;
  const int ldstA = tid * 8;
  const int ldstB = 4096 + tid * 8;

  const int sprime = laneS ^ ((laneR >> 1) & 3);
  const int aoff = (wm * 64 + laneR) * 32 + sprime * 8;
  const int boff = 4096 + (wn * 64 + laneR) * 32 + sprime * 8;

  f32x4 acc[4][4] = {};

  #define STAGE_T(KT, DB)                                                         \
    { gload_lds16(Asrc + (KT) * 32, lds + (DB) + ldstA);                          \
      gload_lds16(Bsrc + (KT) * 32, lds + (DB) + ldstB);                          \
      gload_lds16(Bsrc + (KT) * 32 + rowstep128, lds + (DB) + ldstB + 4096); }

  STAGE_T(0, 0);
  STAGE_T(1, 12288);
  asm volatile("s_waitcnt vmcnt(3)" ::: "memory");
  SBAR;
  __builtin_amdgcn_s_barrier();
  SBAR;

  for (int t = 0; t < NT; ++t) {
    const ushort* cb = lds + (t % 3) * 12288;
    const int db2 = ((t + 2) % 3) * 12288;
    const int t2 = (t + 2 < NT) ? t + 2 : t;   // clamped tail: dead dup stages
    bf16x8 a[4], b[4];
    #pragma unroll
    for (int j = 0; j < 4; ++j) b[j] = *(const bf16x8*)(cb + boff + j * 512);
    #pragma unroll
    for (int i = 0; i < 4; ++i) a[i] = *(const bf16x8*)(cb + aoff + i * 512);
    STAGE_T(t2, db2);
    asm volatile("s_waitcnt vmcnt(3)" ::: "memory");   // confirms tile t+1
    SBAR;
    __builtin_amdgcn_s_barrier();
    SBAR;
    __builtin_amdgcn_s_setprio(1);
    #pragma unroll
    for (int i = 0; i < 4; ++i)
      #pragma unroll
      for (int j = 0; j < 4; ++j)
        acc[i][j] = __builtin_amdgcn_mfma_f32_16x16x32_bf16(a[i], b[j], acc[i][j], 0, 0, 0);
    __builtin_amdgcn_s_setprio(0);
    SBAR;
    __builtin_amdgcn_s_barrier();
    SBAR;
  }
  #undef STAGE_T
  asm volatile("s_waitcnt vmcnt(0)" ::: "memory");     // drain dead tail stages

  // ---- epilogue: C/D layout col=lane&15, row=(lane>>4)*4+r ----
  #pragma unroll
  for (int i = 0; i < 4; ++i) {
    const int grow0 = m0 + wm * 64 + i * 16 + (laneS << 2);
    #pragma unroll
    for (int j = 0; j < 4; ++j) {
      const int gcol = n0 + wn * 64 + j * 16 + laneR;
      #pragma unroll
      for (int r = 0; r < 4; ++r) {
        float v = acc[i][j][r];
        if (MODE == 0) {
          if (gcol < 1536) v = (v > 0.f) ? (v + 1.f) : __expf(v);   // phi on q,k
          reinterpret_cast<ushort*>(C)[(size_t)(grow0 + r) * N + gcol] = f2bf(v);
        } else {
          reinterpret_cast<float*>(C)[(size_t)(grow0 + r) * N + gcol] = v + bias[gcol];
        }
      }
    }
  }
}

// ---------------- kv partial: f32-in-LDS staging (convert once), stride-68 pad ------
__global__ __launch_bounds__(256) void kv_partial(const ushort* __restrict__ qkv,
                                                  float* __restrict__ kv_part,
                                                  float* __restrict__ ks_part) {
  const int blk = blockIdx.x;          // 384*4
  const int bh = blk >> 2, sp = blk & 3;
  const int b = bh / 12, h = bh % 12;
  const int tid = threadIdx.x;
  __shared__ float Ks[32 * 68];
  __shared__ float Vs[32 * 68];
  float acc[4][4] = {};                // [m][dq]
  float kacc[4] = {};
  const int dq0 = (tid & 15) * 4, mq0 = (tid >> 4) * 4;
  const int r = tid >> 3, o = (tid & 7) * 8;        // stage: row r, 8 cols from o
  for (int st = 0; st < 256; st += 32) {
    const size_t rowbase = (size_t)(b * 1024 + sp * 256 + st + r) * 2304 + h * 64 + o;
    int4 kraw = *reinterpret_cast<const int4*>(qkv + rowbase + 768);
    int4 vraw = *reinterpret_cast<const int4*>(qkv + rowbase + 1536);
    float kf[8], vf[8];
    {
      const unsigned* kw = reinterpret_cast<const unsigned*>(&kraw);
      const unsigned* vw = reinterpret_cast<const unsigned*>(&vraw);
      #pragma unroll
      for (int w = 0; w < 4; ++w) {
        kf[2 * w]     = bits2f(kw[w] << 16);
        kf[2 * w + 1] = bits2f(kw[w] & 0xffff0000u);
        vf[2 * w]     = bits2f(vw[w] << 16);
        vf[2 * w + 1] = bits2f(vw[w] & 0xffff0000u);
      }
    }
    __syncthreads();                   // prev-iter LDS reads done
    #pragma unroll
    for (int w = 0; w < 8; ++w) {
      Ks[r * 68 + o + w] = kf[w];
      Vs[r * 68 + o + w] = vf[w];
    }
    __syncthreads();                   // tile present
    #pragma unroll 8
    for (int s = 0; s < 32; ++s) {
      f32x4 kk = *reinterpret_cast<const f32x4*>(&Ks[s * 68 + dq0]);
      f32x4 vv = *reinterpret_cast<const f32x4*>(&Vs[s * 68 + mq0]);
      #pragma unroll
      for (int jm = 0; jm < 4; ++jm)
        #pragma unroll
        for (int id = 0; id < 4; ++id)
          acc[jm][id] += vv[jm] * kk[id];
      if (mq0 == 0) {
        #pragma unroll
        for (int id = 0; id < 4; ++id) kacc[id] += kk[id];
      }
    }
  }
  float* kvp = kv_part + ((size_t)sp * 384 + bh) * 4096;
  #pragma unroll
  for (int jm = 0; jm < 4; ++jm)
    #pragma unroll
    for (int id = 0; id < 4; ++id)
      kvp[(mq0 + jm) * 64 + dq0 + id] = acc[jm][id];
  if (mq0 == 0) {
    #pragma unroll
    for (int id = 0; id < 4; ++id)
      ks_part[((size_t)sp * 384 + bh) * 64 + dq0 + id] = kacc[id];
  }
}

// ---------------- reduce splits: kv -> bf16 [bh][m][dq], ksum += 1.0 (pad token) ----
__global__ __launch_bounds__(256) void kv_reduce(const float* __restrict__ kv_part,
                                                 const float* __restrict__ ks_part,
                                                 ushort* __restrict__ kv_bf,
                                                 float* __restrict__ ksum) {
  int i = blockIdx.x * 256 + threadIdx.x;
  if (i < 384 * 4096) {
    float s = 0.f;
    #pragma unroll
    for (int p = 0; p < 4; ++p) s += kv_part[(size_t)p * (384 * 4096) + i];
    kv_bf[i] = f2bf(s);
  }
  if (i < 384 * 64) {
    float s = 1.0f;    // phi(0)=1 contribution of the zero padding token
    #pragma unroll
    for (int p = 0; p < 4; ++p) s += ks_part[(size_t)p * (384 * 64) + i];
    ksum[i] = s;
  }
}

// ---------------- attention (r13-verified: swizzled Qs/KVs, vectorized z-dot) -------
// z-dot pairing: LDS slot (s^tx7) of row tid CONTAINS global slot s (staging wrote
// source slot dsl^(qr&7) into linear dest slot dsl) -> multiply by ks_lds[s*8+...].
__global__ __launch_bounds__(256) void attn_kernel(const ushort* __restrict__ qkv,
                                                   const ushort* __restrict__ kv_bf,
                                                   const float* __restrict__ ksum,
                                                   ushort* __restrict__ attn) {
  const int blk = blockIdx.x;          // 384*8
  const int bh = blk >> 3, tb = blk & 7;
  const int b = bh / 12, h = bh % 12;
  const int row0 = b * 1024 + tb * 128;
  __shared__ ushort Qs[128 * 64];
  __shared__ ushort KVs[64 * 64];      // [m][dq]
  __shared__ float zs[128];
  __shared__ float ks_lds[64];
  const int tid = threadIdx.x;
  const int lane = tid & 63, w = tid >> 6;
  #pragma unroll
  for (int j = 0; j < 4; ++j) {
    int c = j * 256 + tid;
    int qr = c >> 3, dsl = c & 7;
    int ssl = dsl ^ (qr & 7);
    gload_lds16(qkv + (size_t)(row0 + qr) * 2304 + h * 64 + ssl * 8, &Qs[c * 8]);
  }
  #pragma unroll
  for (int j = 0; j < 2; ++j) {
    int c = j * 256 + tid;
    int mr = c >> 3, dsl = c & 7;
    int ssl = dsl ^ (mr & 7);
    gload_lds16(kv_bf + (size_t)bh * 4096 + mr * 64 + ssl * 8, &KVs[c * 8]);
  }
  if (tid < 64) ks_lds[tid] = ksum[bh * 64 + tid];
  asm volatile("s_waitcnt vmcnt(0)" ::: "memory");
  __syncthreads();
  if (tid < 128) {
    float d = 0.f;
    const int tx7 = tid & 7;
    #pragma unroll
    for (int s = 0; s < 8; ++s) {
      int4 raw = *reinterpret_cast<const int4*>(&Qs[tid * 64 + ((s ^ tx7) << 3)]);
      const unsigned* wds = reinterpret_cast<const unsigned*>(&raw);
      #pragma unroll
      for (int w2 = 0; w2 < 4; ++w2) {
        d += bits2f(wds[w2] << 16) * ks_lds[s * 8 + 2 * w2];
        d += bits2f(wds[w2] & 0xffff0000u) * ks_lds[s * 8 + 2 * w2 + 1];
      }
    }
    zs[tid] = 1.f / (d + 1e-6f);
  }
  __syncthreads();
  f32x4 acc[2][4] = {};
  const int lr7 = (lane & 15) & 7;
  #pragma unroll
  for (int ks = 0; ks < 2; ++ks) {
    const int sxor = ((ks * 4 + (lane >> 4)) ^ lr7) << 3;
    bf16x8 a[2], bb[4];
    #pragma unroll
    for (int i = 0; i < 2; ++i)
      a[i] = *reinterpret_cast<const bf16x8*>(&Qs[(w * 32 + i * 16 + (lane & 15)) * 64 + sxor]);
    #pragma unroll
    for (int j = 0; j < 4; ++j)
      bb[j] = *reinterpret_cast<const bf16x8*>(&KVs[(j * 16 + (lane & 15)) * 64 + sxor]);
    #pragma unroll
    for (int i = 0; i < 2; ++i)
      #pragma unroll
      for (int j = 0; j < 4; ++j)
        acc[i][j] = __builtin_amdgcn_mfma_f32_16x16x32_bf16(a[i], bb[j], acc[i][j], 0, 0, 0);
  }
  #pragma unroll
  for (int i = 0; i < 2; ++i) {
    const int t0 = w * 32 + i * 16 + ((lane >> 4) << 2);
    #pragma unroll
    for (int j = 0; j < 4; ++j) {
      const int m = j * 16 + (lane & 15);
      #pragma unroll
      for (int r = 0; r < 4; ++r) {
        float v = acc[i][j][r] * zs[t0 + r];
        attn[(size_t)(row0 + t0 + r) * 768 + h * 64 + m] = f2bf(v);
      }
    }
  }
}

// ---------------- launch ----------------
extern "C" void kernel_launch(void* const* d_in, const int* in_sizes, int n_in,
                              void* d_out, int out_size, void* d_ws, size_t ws_size,
                              hipStream_t stream) {
  (void)in_sizes; (void)n_in; (void)out_size; (void)ws_size;
  const float* x    = (const float*)d_in[0];
  const float* Wqkv = (const float*)d_in[1];
  const float* Wout = (const float*)d_in[2];
  const float* bout = (const float*)d_in[3];
  float* out = (float*)d_out;
  char* ws = (char*)d_ws;

  // workspace layout (total ~210 MB); region 0 reused by time-disjoint buffers
  ushort* xbf    = (ushort*)(ws);               // 50,331,648 B : x bf16 [32768][768]
  ushort* wqkvT  = (ushort*)(ws + 50331648);    //  3,538,944 B : W_qkv^T bf16 [2304][768]
  ushort* woutT  = (ushort*)(ws + 53870592);    //  1,179,648 B : W_out^T bf16 [768][768]
  ushort* qkv    = (ushort*)(ws + 55050240);    // 150,994,944 B: phi(q)|phi(k)|v bf16 [32768][2304]
  float*  ksp    = (float*) (ws + 206045184);   //    393,216 B : ksum partials [4][384][64]
  ushort* kvbf   = (ushort*)(ws + 206438400);   //  3,145,728 B : kv bf16 [384][64m][64dq]
  float*  ksum   = (float*) (ws + 209584128);   //     98,304 B : ksum+1 [384][64]
  float*  kvpart = (float*)(ws);                // 25,165,824 B : overlays xbf (dead after gemm1)
  ushort* attn   = (ushort*)(ws);               // 50,331,648 B : overlays kvpart (dead after kv_reduce)

  static const int LDS3 = 73728;    // 3 bufs x 24 KB
  hipFuncSetAttribute(reinterpret_cast<const void*>(&gemm3b<0>),
                      hipFuncAttributeMaxDynamicSharedMemorySize, LDS3);
  hipFuncSetAttribute(reinterpret_cast<const void*>(&gemm3b<1>),
                      hipFuncAttributeMaxDynamicSharedMemorySize, LDS3);

  cvt_f32_bf16<<<24576, 256, 0, stream>>>(x, xbf, 6291456);
  transpose_cvt2<<<dim3(72, 24, 2), 256, 0, stream>>>(Wqkv, wqkvT, Wout, woutT);
  // GEMM1: 128x256 tiles -> grid 256x9 = 2304 (cpx=288), 2 blocks/CU  [141 us]
  gemm3b<0><<<2304, 512, LDS3, stream>>>(xbf, wqkvT, qkv, nullptr, 2304, 768, 9, 288);
  kv_partial<<<1536, 256, 0, stream>>>(qkv, kvpart, ksp);
  kv_reduce<<<6144, 256, 0, stream>>>(kvpart, ksp, kvbf, ksum);
  attn_kernel<<<3072, 256, 0, stream>>>(qkv, kvbf, ksum, attn);
  // GEMM2: 128x256 tiles -> grid 256x3 = 768 (cpx=96)
  gemm3b<1><<<768, 512, LDS3, stream>>>(attn, woutT, out, bout, 768, 768, 3, 96);
}